// Round 4
// baseline (160.691 us; speedup 1.0000x reference)
//
#include <hip/hip_runtime.h>
#include <math.h>

// Capsule dynamic routing, fully fused, 4-BATCH BLOCKED: one block of 512
// threads per (c, batch-quad). B=256, C=10, N=1152, Din=8, U=16, 3 iters.
//
// Round-4. Root cause of rounds 1-3's spills finally identified: VGPR_Count
// tracked exactly HALF the launch-bounds cap each round (cap 128 -> alloc 64,
// cap 256 -> alloc 128, both with ~100 MB scratch traffic). __launch_bounds__
// only sets a MINIMUM waves/EU; LLVM's scheduler still TARGETS a higher
// occupancy and spills to reach it. Fix: pin occupancy from both sides with
// __attribute__((amdgpu_waves_per_eu(2, 2))) -- max=2 waves/EU forbids the
// 4-wave target, so the allocator may use up to 256 regs for the ~230-reg
// live set (36 named u_hat float4 = 144, one UHC group in flight = 64,
// misc ~20). Everything else is identical to round 3 (passing, absmax 2e-7):
//  * 4-batch W reuse: each W float4 feeds 16 FMAs; L2 W traffic 1.5 GB
//    (round 0) -> 0.38 GB.
//  * u_hat in NAMED float4 registers (array form spills); sched_barrier(0)
//    after each UHC group caps the in-flight window at one group.
//  * b logits in LDS (b_s[4][1152]); x direct from global (L2-resident);
//    iteration 0 peeled (softmax(ones) == 1/1152).

#define BATCH 256
#define CAPS  10
#define NIN   1152
#define DIN   8
#define UDIM  16
#define TPB   512

__global__ __launch_bounds__(TPB) __attribute__((amdgpu_waves_per_eu(2, 2)))
void capsule_routing_kernel(
    const float* __restrict__ x,   // (B, N, Din)
    const float* __restrict__ W,   // (C, N, Din, U)
    float* __restrict__ out)       // (B, C, U)
{
    const int gblk = blockIdx.x;      // c-major for L2 W-locality
    const int c    = gblk >> 6;       // 0..9
    const int bq   = gblk & 63;       // 0..63  (batch quad)
    const int b0   = bq << 2;
    const int t    = threadIdx.x;     // 0..511
    const int ub   = (t & 3) << 2;    // u base: 0,4,8,12
    const int gg   = t >> 2;          // 0..127 (n residue)
    const int wave = t >> 6;          // 0..7

    __shared__ float b_s[4][NIN];       // routing logits, per batch (18.4 KB)
    __shared__ float redB[4][8];        // per-wave exp-sum partials
    __shared__ float ps[4][8][UDIM];    // per-wave partial s
    __shared__ float v_s[4][UDIM];      // squashed output

    const float* Wc = W + (size_t)c * (NIN * DIN * UDIM);
    const float* xA = x + (size_t)b0 * (NIN * DIN);
    const float* xB = xA + (NIN * DIN);
    const float* xC = xB + (NIN * DIN);
    const float* xD = xC + (NIN * DIN);

    // u_hat in 36 NAMED float4 registers (array form spills)
    float4 uA0,uA1,uA2,uA3,uA4,uA5,uA6,uA7,uA8;
    float4 uB0,uB1,uB2,uB3,uB4,uB5,uB6,uB7,uB8;
    float4 uC0,uC1,uC2,uC3,uC4,uC5,uC6,uC7,uC8;
    float4 uD0,uD1,uD2,uD3,uD4,uD5,uD6,uD7,uD8;

#define UHC(K, DA, DB, DC, DD) { \
    const int n_ = gg + 128 * (K); \
    const float4* wr_ = (const float4*)(Wc + n_ * (DIN * UDIM) + ub); \
    const float4 xa_ = ((const float4*)(xA + n_ * DIN))[0]; \
    const float4 xa2_ = ((const float4*)(xA + n_ * DIN))[1]; \
    const float4 xb_ = ((const float4*)(xB + n_ * DIN))[0]; \
    const float4 xb2_ = ((const float4*)(xB + n_ * DIN))[1]; \
    const float4 xc_ = ((const float4*)(xC + n_ * DIN))[0]; \
    const float4 xc2_ = ((const float4*)(xC + n_ * DIN))[1]; \
    const float4 xd_ = ((const float4*)(xD + n_ * DIN))[0]; \
    const float4 xd2_ = ((const float4*)(xD + n_ * DIN))[1]; \
    float4 w0_ = wr_[0], w1_ = wr_[4], w2_ = wr_[8], w3_ = wr_[12]; \
    float4 ra_, rb_, rc_, rd_; \
    ra_.x = xa_.x*w0_.x + xa_.y*w1_.x + xa_.z*w2_.x + xa_.w*w3_.x; \
    ra_.y = xa_.x*w0_.y + xa_.y*w1_.y + xa_.z*w2_.y + xa_.w*w3_.y; \
    ra_.z = xa_.x*w0_.z + xa_.y*w1_.z + xa_.z*w2_.z + xa_.w*w3_.z; \
    ra_.w = xa_.x*w0_.w + xa_.y*w1_.w + xa_.z*w2_.w + xa_.w*w3_.w; \
    rb_.x = xb_.x*w0_.x + xb_.y*w1_.x + xb_.z*w2_.x + xb_.w*w3_.x; \
    rb_.y = xb_.x*w0_.y + xb_.y*w1_.y + xb_.z*w2_.y + xb_.w*w3_.y; \
    rb_.z = xb_.x*w0_.z + xb_.y*w1_.z + xb_.z*w2_.z + xb_.w*w3_.z; \
    rb_.w = xb_.x*w0_.w + xb_.y*w1_.w + xb_.z*w2_.w + xb_.w*w3_.w; \
    rc_.x = xc_.x*w0_.x + xc_.y*w1_.x + xc_.z*w2_.x + xc_.w*w3_.x; \
    rc_.y = xc_.x*w0_.y + xc_.y*w1_.y + xc_.z*w2_.y + xc_.w*w3_.y; \
    rc_.z = xc_.x*w0_.z + xc_.y*w1_.z + xc_.z*w2_.z + xc_.w*w3_.z; \
    rc_.w = xc_.x*w0_.w + xc_.y*w1_.w + xc_.z*w2_.w + xc_.w*w3_.w; \
    rd_.x = xd_.x*w0_.x + xd_.y*w1_.x + xd_.z*w2_.x + xd_.w*w3_.x; \
    rd_.y = xd_.x*w0_.y + xd_.y*w1_.y + xd_.z*w2_.y + xd_.w*w3_.y; \
    rd_.z = xd_.x*w0_.z + xd_.y*w1_.z + xd_.z*w2_.z + xd_.w*w3_.z; \
    rd_.w = xd_.x*w0_.w + xd_.y*w1_.w + xd_.z*w2_.w + xd_.w*w3_.w; \
    w0_ = wr_[16]; w1_ = wr_[20]; w2_ = wr_[24]; w3_ = wr_[28]; \
    ra_.x += xa2_.x*w0_.x + xa2_.y*w1_.x + xa2_.z*w2_.x + xa2_.w*w3_.x; \
    ra_.y += xa2_.x*w0_.y + xa2_.y*w1_.y + xa2_.z*w2_.y + xa2_.w*w3_.y; \
    ra_.z += xa2_.x*w0_.z + xa2_.y*w1_.z + xa2_.z*w2_.z + xa2_.w*w3_.z; \
    ra_.w += xa2_.x*w0_.w + xa2_.y*w1_.w + xa2_.z*w2_.w + xa2_.w*w3_.w; \
    rb_.x += xb2_.x*w0_.x + xb2_.y*w1_.x + xb2_.z*w2_.x + xb2_.w*w3_.x; \
    rb_.y += xb2_.x*w0_.y + xb2_.y*w1_.y + xb2_.z*w2_.y + xb2_.w*w3_.y; \
    rb_.z += xb2_.x*w0_.z + xb2_.y*w1_.z + xb2_.z*w2_.z + xb2_.w*w3_.z; \
    rb_.w += xb2_.x*w0_.w + xb2_.y*w1_.w + xb2_.z*w2_.w + xb2_.w*w3_.w; \
    rc_.x += xc2_.x*w0_.x + xc2_.y*w1_.x + xc2_.z*w2_.x + xc2_.w*w3_.x; \
    rc_.y += xc2_.x*w0_.y + xc2_.y*w1_.y + xc2_.z*w2_.y + xc2_.w*w3_.y; \
    rc_.z += xc2_.x*w0_.z + xc2_.y*w1_.z + xc2_.z*w2_.z + xc2_.w*w3_.z; \
    rc_.w += xc2_.x*w0_.w + xc2_.y*w1_.w + xc2_.z*w2_.w + xc2_.w*w3_.w; \
    rd_.x += xd2_.x*w0_.x + xd2_.y*w1_.x + xd2_.z*w2_.x + xd2_.w*w3_.x; \
    rd_.y += xd2_.x*w0_.y + xd2_.y*w1_.y + xd2_.z*w2_.y + xd2_.w*w3_.y; \
    rd_.z += xd2_.x*w0_.z + xd2_.y*w1_.z + xd2_.z*w2_.z + xd2_.w*w3_.z; \
    rd_.w += xd2_.x*w0_.w + xd2_.y*w1_.w + xd2_.z*w2_.w + xd2_.w*w3_.w; \
    DA = ra_; DB = rb_; DC = rc_; DD = rd_; } \
    __builtin_amdgcn_sched_barrier(0);

    UHC(0, uA0, uB0, uC0, uD0)
    UHC(1, uA1, uB1, uC1, uD1)
    UHC(2, uA2, uB2, uC2, uD2)
    UHC(3, uA3, uB3, uC3, uD3)
    UHC(4, uA4, uB4, uC4, uD4)
    UHC(5, uA5, uB5, uC5, uD5)
    UHC(6, uA6, uB6, uC6, uD6)
    UHC(7, uA7, uB7, uC7, uD7)
    UHC(8, uA8, uB8, uC8, uD8)

    float4 pA, pB, pC, pD;
    float leA, leB, leC, leD;

    // ---- reduction helpers ----
#define PSTAGE(MK) { \
    pA.x += __shfl_xor(pA.x, MK); pA.y += __shfl_xor(pA.y, MK); \
    pA.z += __shfl_xor(pA.z, MK); pA.w += __shfl_xor(pA.w, MK); \
    pB.x += __shfl_xor(pB.x, MK); pB.y += __shfl_xor(pB.y, MK); \
    pB.z += __shfl_xor(pB.z, MK); pB.w += __shfl_xor(pB.w, MK); \
    pC.x += __shfl_xor(pC.x, MK); pC.y += __shfl_xor(pC.y, MK); \
    pC.z += __shfl_xor(pC.z, MK); pC.w += __shfl_xor(pC.w, MK); \
    pD.x += __shfl_xor(pD.x, MK); pD.y += __shfl_xor(pD.y, MK); \
    pD.z += __shfl_xor(pD.z, MK); pD.w += __shfl_xor(pD.w, MK); }

#define PRED_WRITE() { \
    PSTAGE(4) PSTAGE(8) PSTAGE(16) PSTAGE(32) \
    if ((t & 63) < 4) { \
        ps[0][wave][ub+0] = pA.x; ps[0][wave][ub+1] = pA.y; \
        ps[0][wave][ub+2] = pA.z; ps[0][wave][ub+3] = pA.w; \
        ps[1][wave][ub+0] = pB.x; ps[1][wave][ub+1] = pB.y; \
        ps[1][wave][ub+2] = pB.z; ps[1][wave][ub+3] = pB.w; \
        ps[2][wave][ub+0] = pC.x; ps[2][wave][ub+1] = pC.y; \
        ps[2][wave][ub+2] = pC.z; ps[2][wave][ub+3] = pC.w; \
        ps[3][wave][ub+0] = pD.x; ps[3][wave][ub+1] = pD.y; \
        ps[3][wave][ub+2] = pD.z; ps[3][wave][ub+3] = pD.w; \
    } }

    // squash: threads 0..63 (wave 0). bi = batch (0..3), u = component.
#define SQUASH(USE_RED, WROUT) { \
    __syncthreads(); \
    if (t < 64) { \
        const int bi_ = t >> 4, u_ = t & 15; \
        float inv_; \
        if (USE_RED) { \
            float es_ = 0.f; \
            es_ += redB[bi_][0]; es_ += redB[bi_][1]; es_ += redB[bi_][2]; es_ += redB[bi_][3]; \
            es_ += redB[bi_][4]; es_ += redB[bi_][5]; es_ += redB[bi_][6]; es_ += redB[bi_][7]; \
            inv_ = 4.0f / es_;               /* 4x lane overcount in le */ \
        } else { \
            inv_ = 1.0f / 1152.0f;           /* softmax(ones) is uniform */ \
        } \
        float s_ = 0.f; \
        s_ += ps[bi_][0][u_]; s_ += ps[bi_][1][u_]; s_ += ps[bi_][2][u_]; s_ += ps[bi_][3][u_]; \
        s_ += ps[bi_][4][u_]; s_ += ps[bi_][5][u_]; s_ += ps[bi_][6][u_]; s_ += ps[bi_][7][u_]; \
        s_ *= inv_; \
        float sq_ = s_ * s_; \
        sq_ += __shfl_xor(sq_, 1); sq_ += __shfl_xor(sq_, 2); \
        sq_ += __shfl_xor(sq_, 4); sq_ += __shfl_xor(sq_, 8); \
        const float sc_ = sq_ / ((1.0f + sq_) * sqrtf(sq_ + 1e-9f)); \
        const float v_ = sc_ * s_; \
        v_s[bi_][u_] = v_; \
        if (WROUT) out[((size_t)(b0 + bi_) * CAPS + c) * UDIM + u_] = v_; \
    } \
    __syncthreads(); }

    // b update: butterfly over the 4 owner lanes; owner lane writes LDS.
#define BUP(K, UA, UB, UC, UD, INIT) { \
    float qa_ = UA.x*vA_.x + UA.y*vA_.y + UA.z*vA_.z + UA.w*vA_.w; \
    float qb_ = UB.x*vB_.x + UB.y*vB_.y + UB.z*vB_.z + UB.w*vB_.w; \
    float qc_ = UC.x*vC_.x + UC.y*vC_.y + UC.z*vC_.z + UC.w*vC_.w; \
    float qd_ = UD.x*vD_.x + UD.y*vD_.y + UD.z*vD_.z + UD.w*vD_.w; \
    qa_ += __shfl_xor(qa_, 1); qa_ += __shfl_xor(qa_, 2); \
    qb_ += __shfl_xor(qb_, 1); qb_ += __shfl_xor(qb_, 2); \
    qc_ += __shfl_xor(qc_, 1); qc_ += __shfl_xor(qc_, 2); \
    qd_ += __shfl_xor(qd_, 1); qd_ += __shfl_xor(qd_, 2); \
    if ((t & 3) == 0) { \
        const int n_ = gg + 128 * (K); \
        if (INIT) { \
            b_s[0][n_] = 1.0f + qa_; b_s[1][n_] = 1.0f + qb_; \
            b_s[2][n_] = 1.0f + qc_; b_s[3][n_] = 1.0f + qd_; \
        } else { \
            b_s[0][n_] += qa_; b_s[1][n_] += qb_; \
            b_s[2][n_] += qc_; b_s[3][n_] += qd_; \
        } \
    } }

#define BUPD_ALL(INIT) { \
    const float4 vA_ = *(const float4*)(&v_s[0][ub]); \
    const float4 vB_ = *(const float4*)(&v_s[1][ub]); \
    const float4 vC_ = *(const float4*)(&v_s[2][ub]); \
    const float4 vD_ = *(const float4*)(&v_s[3][ub]); \
    BUP(0, uA0, uB0, uC0, uD0, INIT) BUP(1, uA1, uB1, uC1, uD1, INIT) \
    BUP(2, uA2, uB2, uC2, uD2, INIT) BUP(3, uA3, uB3, uC3, uD3, INIT) \
    BUP(4, uA4, uB4, uC4, uD4, INIT) BUP(5, uA5, uB5, uC5, uD5, INIT) \
    BUP(6, uA6, uB6, uC6, uD6, INIT) BUP(7, uA7, uB7, uC7, uD7, INIT) \
    BUP(8, uA8, uB8, uC8, uD8, INIT) \
    __syncthreads(); }

#define PADD(UA, UB, UC, UD) { \
    pA.x += UA.x; pA.y += UA.y; pA.z += UA.z; pA.w += UA.w; \
    pB.x += UB.x; pB.y += UB.y; pB.z += UB.z; pB.w += UB.w; \
    pC.x += UC.x; pC.y += UC.y; pC.z += UC.z; pC.w += UC.w; \
    pD.x += UD.x; pD.y += UD.y; pD.z += UD.z; pD.w += UD.w; }

#define ACCE(K, UA, UB, UC, UD) { \
    const float eA_ = expf(b_s[0][gg + 128*(K)]); \
    const float eB_ = expf(b_s[1][gg + 128*(K)]); \
    const float eC_ = expf(b_s[2][gg + 128*(K)]); \
    const float eD_ = expf(b_s[3][gg + 128*(K)]); \
    leA += eA_; leB += eB_; leC += eC_; leD += eD_; \
    pA.x += eA_*UA.x; pA.y += eA_*UA.y; pA.z += eA_*UA.z; pA.w += eA_*UA.w; \
    pB.x += eB_*UB.x; pB.y += eB_*UB.y; pB.z += eB_*UB.z; pB.w += eB_*UB.w; \
    pC.x += eC_*UC.x; pC.y += eC_*UC.y; pC.z += eC_*UC.z; pC.w += eC_*UC.w; \
    pD.x += eD_*UD.x; pD.y += eD_*UD.y; pD.z += eD_*UD.z; pD.w += eD_*UD.w; }

#define LERED_WRITE() { \
    leA += __shfl_xor(leA, 1);  leB += __shfl_xor(leB, 1); \
    leC += __shfl_xor(leC, 1);  leD += __shfl_xor(leD, 1); \
    leA += __shfl_xor(leA, 2);  leB += __shfl_xor(leB, 2); \
    leC += __shfl_xor(leC, 2);  leD += __shfl_xor(leD, 2); \
    leA += __shfl_xor(leA, 4);  leB += __shfl_xor(leB, 4); \
    leC += __shfl_xor(leC, 4);  leD += __shfl_xor(leD, 4); \
    leA += __shfl_xor(leA, 8);  leB += __shfl_xor(leB, 8); \
    leC += __shfl_xor(leC, 8);  leD += __shfl_xor(leD, 8); \
    leA += __shfl_xor(leA, 16); leB += __shfl_xor(leB, 16); \
    leC += __shfl_xor(leC, 16); leD += __shfl_xor(leD, 16); \
    leA += __shfl_xor(leA, 32); leB += __shfl_xor(leB, 32); \
    leC += __shfl_xor(leC, 32); leD += __shfl_xor(leD, 32); \
    if ((t & 63) == 0) { \
        redB[0][wave] = leA; redB[1][wave] = leB; \
        redB[2][wave] = leC; redB[3][wave] = leD; } }

    // ---- iteration 0: c is uniform 1/1152, no exp needed ----
    pA = uA0; pB = uB0; pC = uC0; pD = uD0;
    PADD(uA1, uB1, uC1, uD1) PADD(uA2, uB2, uC2, uD2)
    PADD(uA3, uB3, uC3, uD3) PADD(uA4, uB4, uC4, uD4)
    PADD(uA5, uB5, uC5, uD5) PADD(uA6, uB6, uC6, uD6)
    PADD(uA7, uB7, uC7, uD7) PADD(uA8, uB8, uC8, uD8)
    PRED_WRITE()
    SQUASH(0, 0)
    BUPD_ALL(1)            // b = 1 + u_hat . v0

    // ---- iteration 1 ----
    leA = 0.f; leB = 0.f; leC = 0.f; leD = 0.f;
    pA = make_float4(0.f, 0.f, 0.f, 0.f); pB = make_float4(0.f, 0.f, 0.f, 0.f);
    pC = make_float4(0.f, 0.f, 0.f, 0.f); pD = make_float4(0.f, 0.f, 0.f, 0.f);
    ACCE(0, uA0, uB0, uC0, uD0) ACCE(1, uA1, uB1, uC1, uD1)
    ACCE(2, uA2, uB2, uC2, uD2) ACCE(3, uA3, uB3, uC3, uD3)
    ACCE(4, uA4, uB4, uC4, uD4) ACCE(5, uA5, uB5, uC5, uD5)
    ACCE(6, uA6, uB6, uC6, uD6) ACCE(7, uA7, uB7, uC7, uD7)
    ACCE(8, uA8, uB8, uC8, uD8)
    LERED_WRITE()
    PRED_WRITE()
    SQUASH(1, 0)
    BUPD_ALL(0)            // b += u_hat . v1

    // ---- iteration 2 (writes out) ----
    leA = 0.f; leB = 0.f; leC = 0.f; leD = 0.f;
    pA = make_float4(0.f, 0.f, 0.f, 0.f); pB = make_float4(0.f, 0.f, 0.f, 0.f);
    pC = make_float4(0.f, 0.f, 0.f, 0.f); pD = make_float4(0.f, 0.f, 0.f, 0.f);
    ACCE(0, uA0, uB0, uC0, uD0) ACCE(1, uA1, uB1, uC1, uD1)
    ACCE(2, uA2, uB2, uC2, uD2) ACCE(3, uA3, uB3, uC3, uD3)
    ACCE(4, uA4, uB4, uC4, uD4) ACCE(5, uA5, uB5, uC5, uD5)
    ACCE(6, uA6, uB6, uC6, uD6) ACCE(7, uA7, uB7, uC7, uD7)
    ACCE(8, uA8, uB8, uC8, uD8)
    LERED_WRITE()
    PRED_WRITE()
    SQUASH(1, 1)
}

extern "C" void kernel_launch(void* const* d_in, const int* in_sizes, int n_in,
                              void* d_out, int out_size, void* d_ws, size_t ws_size,
                              hipStream_t stream) {
    const float* x = (const float*)d_in[0];   // (256, 1152, 8)
    const float* W = (const float*)d_in[1];   // (10, 1152, 8, 16)
    float* out = (float*)d_out;               // (256, 10, 16)
    capsule_routing_kernel<<<CAPS * (BATCH / 4), TPB, 0, stream>>>(x, W, out);
}

// Round 6
// 137.401 us; speedup vs baseline: 1.1695x; 1.1695x over previous
//
#include <hip/hip_runtime.h>
#include <math.h>

// Capsule dynamic routing, fully fused, 2-BATCH BLOCKED: one block of 512
// threads per (c, batch-pair). B=256, C=10, N=1152, Din=8, U=16, 3 iters.
//
// Round-6 = round-5 resubmitted verbatim (round-5 bench died in container
// acquisition, no data). Allocator saga resolved by cross-round evidence:
//   (512,1)->56 regs no spill | (512,4)->64 regs spill | (512,2)->128 spill
// i.e. the 2nd __launch_bounds__ arg acts as min BLOCKS/CU (CUDA semantics):
// budget = 512-reg pool / (blocks*8waves/4SIMDs). amdgpu_waves_per_eu was
// ignored. Practical per-thread budget on this toolchain: 128 regs.
// => 4-batch (needs >=144 regs for u_hat alone, layout-invariant) is DEAD.
// => 2-batch (72 u_hat floats) under (512,1) [proven-benign budget] fits:
//    peak ~116 = 72 u_hat + 16 W-in-flight + 8 x + 8 acc + misc.
// This file = round-2's kernel (passed, absmax 2.4e-7) with ONLY:
//  * __launch_bounds__(512, 1)
//  * UHC split into two din-halves with sched_barrier(0) between, halving
//    the in-flight load window (8 float4 -> 4) to stay under 128.
// Structure kept: b logits in LDS; x direct from global (L2-resident);
// iteration 0 peeled (softmax(ones)=1/1152); u_hat in NAMED float4 regs.

#define BATCH 256
#define CAPS  10
#define NIN   1152
#define DIN   8
#define UDIM  16
#define TPB   512

__global__ __launch_bounds__(TPB, 1) void capsule_routing_kernel(
    const float* __restrict__ x,   // (B, N, Din)
    const float* __restrict__ W,   // (C, N, Din, U)
    float* __restrict__ out)       // (B, C, U)
{
    const int gblk = blockIdx.x;      // c-major for L2 W-locality
    const int c    = gblk >> 7;       // 0..9
    const int bp   = gblk & 127;      // 0..127  (batch pair)
    const int b0   = bp << 1;
    const int t    = threadIdx.x;     // 0..511
    const int ub   = (t & 3) << 2;    // u base: 0,4,8,12
    const int gg   = t >> 2;          // 0..127 (n residue)
    const int wave = t >> 6;          // 0..7

    __shared__ float b_s[2][NIN];       // routing logits, per batch (9.2 KB)
    __shared__ float redB[2][8];        // per-wave exp-sum partials, per batch
    __shared__ float ps[2][8][UDIM];    // per-wave partial s, per batch
    __shared__ float v_s[2][UDIM];      // squashed output, per batch

    const float* Wc = W + (size_t)c * (NIN * DIN * UDIM);
    const float* xA = x + (size_t)b0 * (NIN * DIN);
    const float* xB = xA + (NIN * DIN);

    // u_hat in 18 NAMED float4 registers (array form spills)
    float4 uA0,uA1,uA2,uA3,uA4,uA5,uA6,uA7,uA8;
    float4 uB0,uB1,uB2,uB3,uB4,uB5,uB6,uB7,uB8;

#define UHC(K, DA, DB) { \
    const int n_ = gg + 128 * (K); \
    const float4* wr_ = (const float4*)(Wc + n_ * (DIN * UDIM) + ub); \
    float4 a_, d_; \
    { /* din 0..3 */ \
        const float4 xa_ = ((const float4*)(xA + n_ * DIN))[0]; \
        const float4 ya_ = ((const float4*)(xB + n_ * DIN))[0]; \
        const float4 w0_ = wr_[0], w1_ = wr_[4], w2_ = wr_[8], w3_ = wr_[12]; \
        a_.x = xa_.x*w0_.x + xa_.y*w1_.x + xa_.z*w2_.x + xa_.w*w3_.x; \
        a_.y = xa_.x*w0_.y + xa_.y*w1_.y + xa_.z*w2_.y + xa_.w*w3_.y; \
        a_.z = xa_.x*w0_.z + xa_.y*w1_.z + xa_.z*w2_.z + xa_.w*w3_.z; \
        a_.w = xa_.x*w0_.w + xa_.y*w1_.w + xa_.z*w2_.w + xa_.w*w3_.w; \
        d_.x = ya_.x*w0_.x + ya_.y*w1_.x + ya_.z*w2_.x + ya_.w*w3_.x; \
        d_.y = ya_.x*w0_.y + ya_.y*w1_.y + ya_.z*w2_.y + ya_.w*w3_.y; \
        d_.z = ya_.x*w0_.z + ya_.y*w1_.z + ya_.z*w2_.z + ya_.w*w3_.z; \
        d_.w = ya_.x*w0_.w + ya_.y*w1_.w + ya_.z*w2_.w + ya_.w*w3_.w; \
    } \
    __builtin_amdgcn_sched_barrier(0); \
    { /* din 4..7 */ \
        const float4 xb_ = ((const float4*)(xA + n_ * DIN))[1]; \
        const float4 yb_ = ((const float4*)(xB + n_ * DIN))[1]; \
        const float4 w0_ = wr_[16], w1_ = wr_[20], w2_ = wr_[24], w3_ = wr_[28]; \
        a_.x += xb_.x*w0_.x + xb_.y*w1_.x + xb_.z*w2_.x + xb_.w*w3_.x; \
        a_.y += xb_.x*w0_.y + xb_.y*w1_.y + xb_.z*w2_.y + xb_.w*w3_.y; \
        a_.z += xb_.x*w0_.z + xb_.y*w1_.z + xb_.z*w2_.z + xb_.w*w3_.z; \
        a_.w += xb_.x*w0_.w + xb_.y*w1_.w + xb_.z*w2_.w + xb_.w*w3_.w; \
        d_.x += yb_.x*w0_.x + yb_.y*w1_.x + yb_.z*w2_.x + yb_.w*w3_.x; \
        d_.y += yb_.x*w0_.y + yb_.y*w1_.y + yb_.z*w2_.y + yb_.w*w3_.y; \
        d_.z += yb_.x*w0_.z + yb_.y*w1_.z + yb_.z*w2_.z + yb_.w*w3_.z; \
        d_.w += yb_.x*w0_.w + yb_.y*w1_.w + yb_.z*w2_.w + yb_.w*w3_.w; \
    } \
    DA = a_; DB = d_; } \
    __builtin_amdgcn_sched_barrier(0);

    UHC(0, uA0, uB0)
    UHC(1, uA1, uB1)
    UHC(2, uA2, uB2)
    UHC(3, uA3, uB3)
    UHC(4, uA4, uB4)
    UHC(5, uA5, uB5)
    UHC(6, uA6, uB6)
    UHC(7, uA7, uB7)
    UHC(8, uA8, uB8)

    float4 pA, pB;
    float leA, leB;

    // ---- reduction helpers ----
#define PSTAGE(MK) { \
    pA.x += __shfl_xor(pA.x, MK); pA.y += __shfl_xor(pA.y, MK); \
    pA.z += __shfl_xor(pA.z, MK); pA.w += __shfl_xor(pA.w, MK); \
    pB.x += __shfl_xor(pB.x, MK); pB.y += __shfl_xor(pB.y, MK); \
    pB.z += __shfl_xor(pB.z, MK); pB.w += __shfl_xor(pB.w, MK); }

#define PRED_WRITE() { \
    PSTAGE(4) PSTAGE(8) PSTAGE(16) PSTAGE(32) \
    if ((t & 63) < 4) { \
        ps[0][wave][ub+0] = pA.x; ps[0][wave][ub+1] = pA.y; \
        ps[0][wave][ub+2] = pA.z; ps[0][wave][ub+3] = pA.w; \
        ps[1][wave][ub+0] = pB.x; ps[1][wave][ub+1] = pB.y; \
        ps[1][wave][ub+2] = pB.z; ps[1][wave][ub+3] = pB.w; \
    } }

    // squash: threads 0..31 (wave 0). bi = batch, u = component.
#define SQUASH(USE_RED, WROUT) { \
    __syncthreads(); \
    if (t < 32) { \
        const int bi_ = t >> 4, u_ = t & 15; \
        float inv_; \
        if (USE_RED) { \
            float es_ = 0.f; \
            es_ += redB[bi_][0]; es_ += redB[bi_][1]; es_ += redB[bi_][2]; es_ += redB[bi_][3]; \
            es_ += redB[bi_][4]; es_ += redB[bi_][5]; es_ += redB[bi_][6]; es_ += redB[bi_][7]; \
            inv_ = 4.0f / es_;               /* 4x lane overcount in le */ \
        } else { \
            inv_ = 1.0f / 1152.0f;           /* softmax(ones) is uniform */ \
        } \
        float s_ = 0.f; \
        s_ += ps[bi_][0][u_]; s_ += ps[bi_][1][u_]; s_ += ps[bi_][2][u_]; s_ += ps[bi_][3][u_]; \
        s_ += ps[bi_][4][u_]; s_ += ps[bi_][5][u_]; s_ += ps[bi_][6][u_]; s_ += ps[bi_][7][u_]; \
        s_ *= inv_; \
        float sq_ = s_ * s_; \
        sq_ += __shfl_xor(sq_, 1); sq_ += __shfl_xor(sq_, 2); \
        sq_ += __shfl_xor(sq_, 4); sq_ += __shfl_xor(sq_, 8); \
        const float sc_ = sq_ / ((1.0f + sq_) * sqrtf(sq_ + 1e-9f)); \
        const float v_ = sc_ * s_; \
        v_s[bi_][u_] = v_; \
        if (WROUT) out[((size_t)(b0 + bi_) * CAPS + c) * UDIM + u_] = v_; \
    } \
    __syncthreads(); }

    // b update: butterfly over the 4 owner lanes; owner lane writes LDS.
#define BUP(K, UA, UB, INIT) { \
    float qa_ = UA.x*vA_.x + UA.y*vA_.y + UA.z*vA_.z + UA.w*vA_.w; \
    float qb_ = UB.x*vB_.x + UB.y*vB_.y + UB.z*vB_.z + UB.w*vB_.w; \
    qa_ += __shfl_xor(qa_, 1); qa_ += __shfl_xor(qa_, 2); \
    qb_ += __shfl_xor(qb_, 1); qb_ += __shfl_xor(qb_, 2); \
    if ((t & 3) == 0) { \
        const int n_ = gg + 128 * (K); \
        if (INIT) { b_s[0][n_] = 1.0f + qa_; b_s[1][n_] = 1.0f + qb_; } \
        else      { b_s[0][n_] += qa_;       b_s[1][n_] += qb_; } \
    } }

#define BUPD_ALL(INIT) { \
    const float4 vA_ = *(const float4*)(&v_s[0][ub]); \
    const float4 vB_ = *(const float4*)(&v_s[1][ub]); \
    BUP(0, uA0, uB0, INIT) BUP(1, uA1, uB1, INIT) \
    BUP(2, uA2, uB2, INIT) BUP(3, uA3, uB3, INIT) \
    BUP(4, uA4, uB4, INIT) BUP(5, uA5, uB5, INIT) \
    BUP(6, uA6, uB6, INIT) BUP(7, uA7, uB7, INIT) \
    BUP(8, uA8, uB8, INIT) \
    __syncthreads(); }

#define PADD(UA, UB) { \
    pA.x += UA.x; pA.y += UA.y; pA.z += UA.z; pA.w += UA.w; \
    pB.x += UB.x; pB.y += UB.y; pB.z += UB.z; pB.w += UB.w; }

#define ACCE(K, UA, UB) { \
    const float eA_ = expf(b_s[0][gg + 128*(K)]); \
    const float eB_ = expf(b_s[1][gg + 128*(K)]); \
    leA += eA_; leB += eB_; \
    pA.x += eA_*UA.x; pA.y += eA_*UA.y; pA.z += eA_*UA.z; pA.w += eA_*UA.w; \
    pB.x += eB_*UB.x; pB.y += eB_*UB.y; pB.z += eB_*UB.z; pB.w += eB_*UB.w; }

#define LERED_WRITE() { \
    leA += __shfl_xor(leA, 1);  leB += __shfl_xor(leB, 1); \
    leA += __shfl_xor(leA, 2);  leB += __shfl_xor(leB, 2); \
    leA += __shfl_xor(leA, 4);  leB += __shfl_xor(leB, 4); \
    leA += __shfl_xor(leA, 8);  leB += __shfl_xor(leB, 8); \
    leA += __shfl_xor(leA, 16); leB += __shfl_xor(leB, 16); \
    leA += __shfl_xor(leA, 32); leB += __shfl_xor(leB, 32); \
    if ((t & 63) == 0) { redB[0][wave] = leA; redB[1][wave] = leB; } }

    // ---- iteration 0: c is uniform 1/1152, no exp needed ----
    pA = uA0; pB = uB0;
    PADD(uA1, uB1) PADD(uA2, uB2) PADD(uA3, uB3) PADD(uA4, uB4)
    PADD(uA5, uB5) PADD(uA6, uB6) PADD(uA7, uB7) PADD(uA8, uB8)
    PRED_WRITE()
    SQUASH(0, 0)
    BUPD_ALL(1)            // b = 1 + u_hat . v0

    // ---- iteration 1 ----
    leA = 0.f; leB = 0.f;
    pA = make_float4(0.f, 0.f, 0.f, 0.f); pB = make_float4(0.f, 0.f, 0.f, 0.f);
    ACCE(0, uA0, uB0) ACCE(1, uA1, uB1) ACCE(2, uA2, uB2)
    ACCE(3, uA3, uB3) ACCE(4, uA4, uB4) ACCE(5, uA5, uB5)
    ACCE(6, uA6, uB6) ACCE(7, uA7, uB7) ACCE(8, uA8, uB8)
    LERED_WRITE()
    PRED_WRITE()
    SQUASH(1, 0)
    BUPD_ALL(0)            // b += u_hat . v1

    // ---- iteration 2 (writes out) ----
    leA = 0.f; leB = 0.f;
    pA = make_float4(0.f, 0.f, 0.f, 0.f); pB = make_float4(0.f, 0.f, 0.f, 0.f);
    ACCE(0, uA0, uB0) ACCE(1, uA1, uB1) ACCE(2, uA2, uB2)
    ACCE(3, uA3, uB3) ACCE(4, uA4, uB4) ACCE(5, uA5, uB5)
    ACCE(6, uA6, uB6) ACCE(7, uA7, uB7) ACCE(8, uA8, uB8)
    LERED_WRITE()
    PRED_WRITE()
    SQUASH(1, 1)
}

extern "C" void kernel_launch(void* const* d_in, const int* in_sizes, int n_in,
                              void* d_out, int out_size, void* d_ws, size_t ws_size,
                              hipStream_t stream) {
    const float* x = (const float*)d_in[0];   // (256, 1152, 8)
    const float* W = (const float*)d_in[1];   // (10, 1152, 8, 16)
    float* out = (float*)d_out;               // (256, 10, 16)
    capsule_routing_kernel<<<CAPS * (BATCH / 2), TPB, 0, stream>>>(x, W, out);
}